// Round 1
// 582.794 us; speedup vs baseline: 1.0053x; 1.0053x over previous
//
#include <hip/hip_runtime.h>

#define MM 32
#define NN 2048
#define NJ 6144
#define HH 16
#define DD 128
#define LL 32768

typedef __attribute__((ext_vector_type(8))) short bf16x8;
typedef __attribute__((ext_vector_type(4))) short bf16x4s;
typedef __attribute__((ext_vector_type(4))) float f32x4;

static __device__ __forceinline__ short f2bf(float f) {
    union { float f; unsigned u; } v; v.f = f;
    unsigned r = v.u + 0x7FFFu + ((v.u >> 16) & 1u);
    return (short)(r >> 16);
}

// ---------------- Kernel A: RMSNorm, write x_norm transposed [n][m] ----------------
__global__ __launch_bounds__(256) void k_rms(const float* __restrict__ X,
                                             float* __restrict__ xT) {
    const int m = blockIdx.x, t = threadIdx.x;
    const float4* xr = (const float4*)(X + m * NN);
    float4 a = xr[t * 2], b = xr[t * 2 + 1];
    float s = a.x*a.x + a.y*a.y + a.z*a.z + a.w*a.w
            + b.x*b.x + b.y*b.y + b.z*b.z + b.w*b.w;
    for (int o = 32; o; o >>= 1) s += __shfl_down(s, o);
    __shared__ float red[4];
    if ((t & 63) == 0) red[t >> 6] = s;
    __syncthreads();
    float rs = rsqrtf((red[0] + red[1] + red[2] + red[3]) * (1.0f / NN));
    int n0 = t * 8;
    xT[(n0 + 0) * MM + m] = a.x * rs;
    xT[(n0 + 1) * MM + m] = a.y * rs;
    xT[(n0 + 2) * MM + m] = a.z * rs;
    xT[(n0 + 3) * MM + m] = a.w * rs;
    xT[(n0 + 4) * MM + m] = b.x * rs;
    xT[(n0 + 5) * MM + m] = b.y * rs;
    xT[(n0 + 6) * MM + m] = b.z * rs;
    xT[(n0 + 7) * MM + m] = b.w * rs;
}

// ---------------- Kernel B: QKV GEMM, thread-per-column, K-split partials ----------------
__global__ __launch_bounds__(256) void k_qkv(const float* __restrict__ xT,
                                             const float* __restrict__ W,
                                             float* __restrict__ part) {
    const int j = blockIdx.x * 256 + threadIdx.x;
    const int nc = blockIdx.y;
    const int n0 = nc * 128;
    float acc[32];
#pragma unroll
    for (int m = 0; m < 32; m++) acc[m] = 0.f;
#pragma unroll 4
    for (int i = 0; i < 128; i++) {
        const float* xr = xT + (size_t)(n0 + i) * MM;   // uniform address -> s_load
        float w = W[(size_t)(n0 + i) * NJ + j];
#pragma unroll
        for (int m = 0; m < 32; m++) acc[m] += xr[m] * w;
    }
    float* o = part + (size_t)nc * (MM * NJ) + j;
#pragma unroll
    for (int m = 0; m < 32; m++) o[(size_t)m * NJ] = acc[m];
}

// ---------------- Kernel C: reduce QKV partials ----------------
__global__ __launch_bounds__(256) void k_qkvred(const float* __restrict__ part,
                                                float* __restrict__ qkv) {
    const int idx = blockIdx.x * 256 + threadIdx.x;
    float s = 0.f;
#pragma unroll
    for (int c = 0; c < 16; c++) s += part[(size_t)c * (MM * NJ) + idx];
    qkv[idx] = s;
}

// ---------------- Kernel D: attention over old cache (rows [P,P+32) masked) --------------
// grid (H=16, SPLITS=32), 256 thr (4 waves). Each wave: 32 l-rows per chunk, 8 chunks.
// v2: K never touches LDS (direct global->reg fragments); V reg-prefetched at chunk
//     start, written to LDS after scores; K(c+1) issued before PV. No barriers in the
//     chunk loop -> loads stay in flight across phases (latency hidden under MFMA).
// LDS (bytes): q_s 0..8704 | v_s 8704 + wave*8704 (x4 = 34816) | w_s 43520 + wave*2560
//              (x4 = 10240) | dred 53760 (512). total 54272.
#define SMEM_D 54272
__global__ __launch_bounds__(256, 2) void k_attn(const float* __restrict__ cK,
                                                 const float* __restrict__ cV,
                                                 const float* __restrict__ qkv,
                                                 const int* __restrict__ Pp,
                                                 float* __restrict__ Opart,
                                                 float* __restrict__ Dpart) {
    extern __shared__ char smem[];
    const int h = blockIdx.x, sp = blockIdx.y;
    const int t = threadIdx.x, lane = t & 63, wave = t >> 6;
    short* q_s  = (short*)smem;
    short* v_s  = (short*)(smem + 8704) + wave * (32 * 136);
    short* w_s  = (short*)(smem + 43520) + wave * (32 * 40);
    float* dred = (float*)(smem + 53760);
    const int P = *Pp;

    const int l15 = lane & 15, q4 = lane >> 4;
    const int row_st = lane >> 5, col4 = (lane & 31) * 4;

    const float* kbase = cK + ((size_t)h * LL + sp * 1024 + wave * 32) * DD;
    const float* vbase = cV + ((size_t)h * LL + sp * 1024 + wave * 32) * DD;

    // ---- prologue: issue K fragment loads for chunk 0 (global -> regs, no LDS) ----
    float4 kraw[2][4][2];
#pragma unroll
    for (int lt = 0; lt < 2; lt++)
#pragma unroll
        for (int kb = 0; kb < 4; kb++) {
            const float* p0 = kbase + (size_t)(lt * 16 + l15) * DD + kb * 32 + q4 * 8;
            kraw[lt][kb][0] = *(const float4*)p0;
            kraw[lt][kb][1] = *(const float4*)(p0 + 4);
        }

    // ---- stage q (fp32 -> bf16), rows padded to 136 shorts ----
    {
        int m = t >> 3, db = (t & 7) * 16;
        const float4* src = (const float4*)(qkv + (size_t)m * NJ + h * DD + db);
        short* dst = q_s + m * 136 + db;
#pragma unroll
        for (int k = 0; k < 4; k++) {
            float4 v = src[k];
            bf16x4s o; o.x = f2bf(v.x); o.y = f2bf(v.y); o.z = f2bf(v.z); o.w = f2bf(v.w);
            *(bf16x4s*)(dst + 4 * k) = o;
        }
    }
    __syncthreads();

    bf16x8 qf[2][4];
#pragma unroll
    for (int mt = 0; mt < 2; mt++)
#pragma unroll
        for (int kb = 0; kb < 4; kb++)
            qf[mt][kb] = *(const bf16x8*)(q_s + (mt * 16 + l15) * 136 + kb * 32 + q4 * 8);

    f32x4 acc[2][8];
#pragma unroll
    for (int mt = 0; mt < 2; mt++)
#pragma unroll
        for (int dt = 0; dt < 8; dt++) acc[mt][dt] = (f32x4){0.f, 0.f, 0.f, 0.f};
    float dacc[2][4] = {{0.f,0.f,0.f,0.f},{0.f,0.f,0.f,0.f}};

    for (int c = 0; c < 8; c++) {
        const int lbase = sp * 1024 + c * 128 + wave * 32;

        // ---- issue V loads for this chunk (consumed after scores) ----
        float4 vraw[16];
        {
            const float* vb_ = vbase + (size_t)c * (128 * DD) + col4;
#pragma unroll
            for (int p = 0; p < 16; p++)
                vraw[p] = *(const float4*)(vb_ + (size_t)(p * 2 + row_st) * DD);
        }

        // ---- convert K (arrived during previous PV) into MFMA fragments ----
        bf16x8 kf[2][4];
#pragma unroll
        for (int lt = 0; lt < 2; lt++)
#pragma unroll
            for (int kb = 0; kb < 4; kb++) {
                float4 a = kraw[lt][kb][0], b = kraw[lt][kb][1];
                bf16x8 o;
                o[0] = f2bf(a.x); o[1] = f2bf(a.y); o[2] = f2bf(a.z); o[3] = f2bf(a.w);
                o[4] = f2bf(b.x); o[5] = f2bf(b.y); o[6] = f2bf(b.z); o[7] = f2bf(b.w);
                kf[lt][kb] = o;
            }

        // ---- scores: S[32m x 32l] via MFMA (regs only), exp + mask + w to LDS ----
#pragma unroll
        for (int lt = 0; lt < 2; lt++) {
            const int lcol = lbase + lt * 16 + l15;
            const bool masked = ((unsigned)(lcol - P)) < 32u;
#pragma unroll
            for (int mt = 0; mt < 2; mt++) {
                f32x4 s = (f32x4){0.f, 0.f, 0.f, 0.f};
#pragma unroll
                for (int kb = 0; kb < 4; kb++)
                    s = __builtin_amdgcn_mfma_f32_16x16x32_bf16(qf[mt][kb], kf[lt][kb], s, 0, 0, 0);
#pragma unroll
                for (int r = 0; r < 4; r++) {
                    float e = __expf(s[r]);
                    if (masked) e = 0.f;
                    dacc[mt][r] += e;
                    w_s[(mt * 16 + q4 * 4 + r) * 40 + lt * 16 + l15] = f2bf(e);
                }
            }
        }

        // ---- V: convert regs -> bf16 LDS (wave-private, in-order DS keeps it safe) ----
#pragma unroll
        for (int p = 0; p < 16; p++) {
            float4 v = vraw[p];
            bf16x4s o; o.x = f2bf(v.x); o.y = f2bf(v.y); o.z = f2bf(v.z); o.w = f2bf(v.w);
            *(bf16x4s*)(v_s + (p * 2 + row_st) * 136 + col4) = o;
        }

        // ---- prefetch K for next chunk (flight hidden under PV + next scores) ----
        if (c < 7) {
            const float* kc = kbase + (size_t)(c + 1) * (128 * DD);
#pragma unroll
            for (int lt = 0; lt < 2; lt++)
#pragma unroll
                for (int kb = 0; kb < 4; kb++) {
                    const float* p0 = kc + (size_t)(lt * 16 + l15) * DD + kb * 32 + q4 * 8;
                    kraw[lt][kb][0] = *(const float4*)p0;
                    kraw[lt][kb][1] = *(const float4*)(p0 + 4);
                }
        }

        // ---- PV: O[32m x 128d] += w[32m x 32l] * V[32l x 128d] ----
        {
            bf16x8 a0 = *(const bf16x8*)(w_s + l15 * 40 + q4 * 8);
            bf16x8 a1 = *(const bf16x8*)(w_s + (16 + l15) * 40 + q4 * 8);
#pragma unroll
            for (int dt = 0; dt < 8; dt++) {
                bf16x8 bv;
#pragma unroll
                for (int jj = 0; jj < 8; jj++)
                    bv[jj] = v_s[(q4 * 8 + jj) * 136 + dt * 16 + l15];
                acc[0][dt] = __builtin_amdgcn_mfma_f32_16x16x32_bf16(a0, bv, acc[0][dt], 0, 0, 0);
                acc[1][dt] = __builtin_amdgcn_mfma_f32_16x16x32_bf16(a1, bv, acc[1][dt], 0, 0, 0);
            }
        }
    }

    // ---- denom: reduce over the 16 l-lanes, stash per-wave in dred ----
#pragma unroll
    for (int mt = 0; mt < 2; mt++)
#pragma unroll
        for (int r = 0; r < 4; r++) {
            float v = dacc[mt][r];
            v += __shfl_xor(v, 1); v += __shfl_xor(v, 2);
            v += __shfl_xor(v, 4); v += __shfl_xor(v, 8);
            if (l15 == 0) dred[wave * 32 + mt * 16 + q4 * 4 + r] = v;
        }

    // ---- cross-wave O reduce in LDS (reuse staging space) ----
    __syncthreads();
    float* buf = (float*)smem;
    if (wave < 2) {
        float* ob = buf + wave * 4096;
#pragma unroll
        for (int mt = 0; mt < 2; mt++)
#pragma unroll
            for (int dt = 0; dt < 8; dt++)
#pragma unroll
                for (int r = 0; r < 4; r++)
                    ob[(mt * 16 + q4 * 4 + r) * 128 + dt * 16 + l15] = acc[mt][dt][r];
    }
    __syncthreads();
    if (wave >= 2) {
        float* ob = buf + (wave - 2) * 4096;
#pragma unroll
        for (int mt = 0; mt < 2; mt++)
#pragma unroll
            for (int dt = 0; dt < 8; dt++)
#pragma unroll
                for (int r = 0; r < 4; r++)
                    ob[(mt * 16 + q4 * 4 + r) * 128 + dt * 16 + l15] += acc[mt][dt][r];
    }
    __syncthreads();
    float* Ob = Opart + ((size_t)h * 32 + sp) * 4096;
    for (int e = t; e < 4096; e += 256) Ob[e] = buf[e] + buf[4096 + e];
    if (t < 32) {
        float d = dred[t] + dred[32 + t] + dred[64 + t] + dred[96 + t];
        Dpart[((size_t)h * 32 + sp) * 32 + t] = d;
    }
}

// ---------------- Kernel E: fp32 new-row attention + merge partials ----------------
__global__ __launch_bounds__(128) void k_final(const float* __restrict__ qkv,
                                               const float* __restrict__ Opart,
                                               const float* __restrict__ Dpart,
                                               float* __restrict__ out) {
    const int m = blockIdx.x, h = blockIdx.y, t = threadIdx.x;
    __shared__ float wnew[32];
    if (t < 32) {
        const float* qr = qkv + (size_t)m * NJ + h * DD;
        const float* kr = qkv + (size_t)t * NJ + 2048 + h * DD;
        float s = 0.f;
#pragma unroll 8
        for (int d = 0; d < 128; d++) s += qr[d] * kr[d];
        wnew[t] = __expf(s);
    }
    __syncthreads();
    const int d = t;
    float num = 0.f, den = 0.f;
#pragma unroll 4
    for (int m2 = 0; m2 < 32; m2++) {
        num += wnew[m2] * qkv[(size_t)m2 * NJ + 4096 + h * DD + d];
        den += wnew[m2];
    }
#pragma unroll 4
    for (int s2 = 0; s2 < 32; s2++) {
        num += Opart[(((size_t)h * 32 + s2) * 32 + m) * 128 + d];
        den += Dpart[((size_t)h * 32 + s2) * 32 + m];
    }
    out[(size_t)m * NN + h * DD + d] = num / den;
}

extern "C" void kernel_launch(void* const* d_in, const int* in_sizes, int n_in,
                              void* d_out, int out_size, void* d_ws, size_t ws_size,
                              hipStream_t stream) {
    const float* X  = (const float*)d_in[0];
    const float* W  = (const float*)d_in[1];
    const float* cK = (const float*)d_in[2];
    const float* cV = (const float*)d_in[3];
    const int*   Pp = (const int*)d_in[4];
    float* ws = (float*)d_ws;

    // ws layout (floats): xT 65536 | qkv_part 16*196608 | qkv 196608 | Opart 16*32*4096 | Dpart 16384
    float* xT    = ws;
    float* qpart = ws + 65536;
    float* qkv   = ws + 3211264;
    float* Opart = ws + 3407872;
    float* Dpart = ws + 5505024;

    k_rms<<<32, 256, 0, stream>>>(X, xT);
    k_qkv<<<dim3(24, 16), 256, 0, stream>>>(xT, W, qpart);
    k_qkvred<<<768, 256, 0, stream>>>(qpart, qkv);
    k_attn<<<dim3(16, 32), 256, SMEM_D, stream>>>(cK, cV, qkv, Pp, Opart, Dpart);
    k_final<<<dim3(32, 16), 128, 0, stream>>>(qkv, Opart, Dpart, (float*)d_out);
}